// Round 6
// baseline (257.752 us; speedup 1.0000x reference)
//
#include <hip/hip_runtime.h>
#include <hip/hip_bf16.h>
#include <stdint.h>

// ---------------------------------------------------------------------------
// MetaMultiHeadSelfAttention: B=4, S=2048, D=1024, H=16, hd=64, causal.
// R13: QKV GEMM 256x256 with the CORRECT m201-style stage ring.
// R12's failure: vmcnt(0) drain each K-tile (2-phase cover). Fix: staggered
// half-tile staging with asymmetric leads -- A[T+1] staged at p0 (consumed
// quadrant-wise, 3-phase cover), B[T+2] staged at p1/p2 (consumed wholly at
// next tile's p0, 7-phase cover), ONE counted vmcnt(4) at p3. WAR ledger:
// A[T+1] overwrites A[T-1] (reads retired T-1 p3); B0/B1[T+2] overwrite
// B[T] rows (reads retired at p0's lgkmcnt+barrier). No drains, no live
// overwrites. O-proj keeps R10's 256x128 triple-buffer kernel (256 blocks
// = 1 exact round). attn4 / vtrans / cvt unchanged (passed, absmax 0.015625).
// ---------------------------------------------------------------------------

typedef __bf16 bf16x8 __attribute__((ext_vector_type(8)));
typedef __bf16 bf16x4 __attribute__((ext_vector_type(4)));
typedef float  f32x4  __attribute__((ext_vector_type(4)));

static __device__ __forceinline__ f32x4 mfma16(bf16x8 a, bf16x8 b, f32x4 c) {
  return __builtin_amdgcn_mfma_f32_16x16x32_bf16(a, b, c, 0, 0, 0);
}

// async 16B/lane global->LDS; LDS dest = wave-uniform base + lane*16
static __device__ __forceinline__ void load16_lds(const void* g, void* l) {
  __builtin_amdgcn_global_load_lds(
      (const __attribute__((address_space(1))) unsigned int*)g,
      (__attribute__((address_space(3))) unsigned int*)l, 16, 0, 0);
}

// ---------------------------------------------------------------------------
// fp32 -> bf16, 8 elems/thread
// ---------------------------------------------------------------------------
__global__ __launch_bounds__(256) void cvt_f32_bf16(
    const float* __restrict__ in, __bf16* __restrict__ out, int n8) {
  int i = blockIdx.x * blockDim.x + threadIdx.x;
  if (i >= n8) return;
  const float4* in4 = (const float4*)in;
  float4 a = in4[2 * i], b = in4[2 * i + 1];
  __bf16 v[8];
  v[0] = (__bf16)a.x; v[1] = (__bf16)a.y; v[2] = (__bf16)a.z; v[3] = (__bf16)a.w;
  v[4] = (__bf16)b.x; v[5] = (__bf16)b.y; v[6] = (__bf16)b.z; v[7] = (__bf16)b.w;
  *(bf16x8*)(out + 8 * i) = *(bf16x8*)v;
}

// all 4 weight matrices in one launch: wq,wk,wv -> wqkv rows, wo -> wob.
// Wq is pre-scaled by 0.125 * log2(e) so attn can use exp2 with no multiply.
__global__ __launch_bounds__(256) void cvt_w(
    const float* __restrict__ w0, const float* __restrict__ w1,
    const float* __restrict__ w2, const float* __restrict__ w3,
    __bf16* __restrict__ wqkv, __bf16* __restrict__ wo) {
  int blk = blockIdx.x;                 // 2048 blocks, 512 per matrix
  int m = blk >> 9;
  const float* src = (m == 0) ? w0 : (m == 1) ? w1 : (m == 2) ? w2 : w3;
  __bf16* dst = (m < 3) ? (wqkv + (size_t)m * (1024 * 1024)) : wo;
  const float scl = (m == 0) ? 0.18033688011112042f : 1.0f;  // 0.125*log2(e)
  int i = (blk & 511) * 256 + threadIdx.x;
  const float4* in4 = (const float4*)src;
  float4 a = in4[2 * i], b = in4[2 * i + 1];
  __bf16 v[8];
  v[0] = (__bf16)(a.x * scl); v[1] = (__bf16)(a.y * scl);
  v[2] = (__bf16)(a.z * scl); v[3] = (__bf16)(a.w * scl);
  v[4] = (__bf16)(b.x * scl); v[5] = (__bf16)(b.y * scl);
  v[6] = (__bf16)(b.z * scl); v[7] = (__bf16)(b.w * scl);
  *(bf16x8*)(dst + 8 * i) = *(bf16x8*)v;
}

// ---------------------------------------------------------------------------
// stage unit: 64 rows x 64 cols bf16 (8 KB) = 1 global_load_lds / thread,
// chunk-XOR swizzle (16B chunk c of row r -> slot c ^ (r&7)).
// ---------------------------------------------------------------------------
static __device__ __forceinline__ void stage_unit(
    const __bf16* __restrict__ X, long grow0, int K, long k0,
    __bf16* lds, int t) {
  const int lane = t & 63, w = t >> 6;
  const int rl = w * 8 + (lane >> 3);                   // row within unit
  const int chunk = (lane & 7) ^ ((lane >> 3) & 7);     // row&7 == (lane>>3)&7
  load16_lds(X + (grow0 + rl) * (long)K + k0 + chunk * 8,
             lds + (w * 8) * 64);                       // wave-uniform base
}

// ---------------------------------------------------------------------------
// 256x256 4-phase GEMM with staggered half-tile ring (QKV).
// 512 threads = 8 waves (2M x 4N), per-wave 128x64 (8 Mfrag x 4 Nfrag).
// LDS = 2 x (A[256][64] + B[256][64]) = 128 KiB.
// ---------------------------------------------------------------------------
template <typename OutT>
__global__ __launch_bounds__(512, 2) void gemm_bt8q(
    const __bf16* __restrict__ A, const __bf16* __restrict__ Bw,
    OutT* __restrict__ C, int M, int N, int K, int NX) {
  __shared__ __align__(16) __bf16 As[2][256 * 64];
  __shared__ __align__(16) __bf16 Bs[2][256 * 64];
  const int t = threadIdx.x;
  const int lane = t & 63, w = t >> 6;
  const int wm = w >> 2, wn = w & 3;        // 2M x 4N waves
  const int l15 = lane & 15, quad = lane >> 4;

  // T1: bijective XCD swizzle (gridDim.x % 8 == 0)
  const int bid = blockIdx.x;
  const int cpx = gridDim.x >> 3;
  const int swz = (bid & 7) * cpx + (bid >> 3);
  const long m0 = (long)(swz / NX) * 256;
  const long n0 = (long)(swz % NX) * 256;

  int aoff[8][2], boff[4][2];
#pragma unroll
  for (int mf = 0; mf < 8; mf++)
#pragma unroll
    for (int ks = 0; ks < 2; ks++)
      aoff[mf][ks] = (wm * 128 + mf * 16 + l15) * 64 + (((ks * 4 + quad) ^ (l15 & 7)) << 3);
#pragma unroll
  for (int nf = 0; nf < 4; nf++)
#pragma unroll
    for (int ks = 0; ks < 2; ks++)
      boff[nf][ks] = (wn * 64 + nf * 16 + l15) * 64 + (((ks * 4 + quad) ^ (l15 & 7)) << 3);

  const int NT = K >> 6;
  // prologue: stage A[0],B[0] (8 units) + B[1] (4 units); vmcnt(4) -> tile0
  // landed, B[1]'s 4 loads stay in flight.
#pragma unroll
  for (int u = 0; u < 4; u++) stage_unit(A,  m0 + u * 64, K, 0,  &As[0][u * 64 * 64], t);
#pragma unroll
  for (int u = 0; u < 4; u++) stage_unit(Bw, n0 + u * 64, K, 0,  &Bs[0][u * 64 * 64], t);
#pragma unroll
  for (int u = 0; u < 4; u++) stage_unit(Bw, n0 + u * 64, K, 64, &Bs[1][u * 64 * 64], t);
  asm volatile("s_waitcnt vmcnt(4)" ::: "memory");
  __builtin_amdgcn_s_barrier();

  f32x4 acc[8][4] = {};
  for (int T = 0; T < NT; T++) {
    const int cur = T & 1;
    __bf16* Ac = &As[cur][0];
    __bf16* Bc = &Bs[cur][0];
    __bf16* An = &As[cur ^ 1][0];
    const bool pf1 = (T + 1 < NT);
    const bool pf2 = (T + 2 < NT);
    const long kn1 = (long)(T + 1) * 64;
    const long kn2 = (long)(T + 2) * 64;

    bf16x8 bfr[4][2];

    // ---- phase 0 : stage A[T+1] (into slot of A[T-1], dead); 12 ds_reads;
    //                MFMA quadrant 0 (mf0,1) ----
    if (pf1) {
#pragma unroll
      for (int u = 0; u < 4; u++) stage_unit(A, m0 + u * 64, K, kn1, An + u * 64 * 64, t);
    }
#pragma unroll
    for (int nf = 0; nf < 4; nf++)
#pragma unroll
      for (int ks = 0; ks < 2; ks++)
        bfr[nf][ks] = *(const bf16x8*)(Bc + boff[nf][ks]);
    {
      bf16x8 a00 = *(const bf16x8*)(Ac + aoff[0][0]);
      bf16x8 a01 = *(const bf16x8*)(Ac + aoff[0][1]);
      bf16x8 a10 = *(const bf16x8*)(Ac + aoff[1][0]);
      bf16x8 a11 = *(const bf16x8*)(Ac + aoff[1][1]);
      __builtin_amdgcn_s_barrier();
      asm volatile("s_waitcnt lgkmcnt(0)" ::: "memory");
      __builtin_amdgcn_sched_barrier(0);
      __builtin_amdgcn_s_setprio(1);
#pragma unroll
      for (int nf = 0; nf < 4; nf++) {
        acc[0][nf] = mfma16(a00, bfr[nf][0], acc[0][nf]);
        acc[0][nf] = mfma16(a01, bfr[nf][1], acc[0][nf]);
        acc[1][nf] = mfma16(a10, bfr[nf][0], acc[1][nf]);
        acc[1][nf] = mfma16(a11, bfr[nf][1], acc[1][nf]);
      }
      __builtin_amdgcn_s_setprio(0);
      __builtin_amdgcn_s_barrier();
    }
    // ---- phase 1 : stage B-half0[T+2] (B[T] rows 0-127, reads retired p0);
    //                MFMA quadrant 1 (mf2,3) ----
    if (pf2) {
#pragma unroll
      for (int u = 0; u < 2; u++) stage_unit(Bw, n0 + u * 64, K, kn2, Bc + u * 64 * 64, t);
    }
    {
      bf16x8 a00 = *(const bf16x8*)(Ac + aoff[2][0]);
      bf16x8 a01 = *(const bf16x8*)(Ac + aoff[2][1]);
      bf16x8 a10 = *(const bf16x8*)(Ac + aoff[3][0]);
      bf16x8 a11 = *(const bf16x8*)(Ac + aoff[3][1]);
      __builtin_amdgcn_s_barrier();
      asm volatile("s_waitcnt lgkmcnt(0)" ::: "memory");
      __builtin_amdgcn_sched_barrier(0);
      __builtin_amdgcn_s_setprio(1);
#pragma unroll
      for (int nf = 0; nf < 4; nf++) {
        acc[2][nf] = mfma16(a00, bfr[nf][0], acc[2][nf]);
        acc[2][nf] = mfma16(a01, bfr[nf][1], acc[2][nf]);
        acc[3][nf] = mfma16(a10, bfr[nf][0], acc[3][nf]);
        acc[3][nf] = mfma16(a11, bfr[nf][1], acc[3][nf]);
      }
      __builtin_amdgcn_s_setprio(0);
      __builtin_amdgcn_s_barrier();
    }
    // ---- phase 2 : stage B-half1[T+2]; MFMA quadrant 2 (mf4,5) ----
    if (pf2) {
#pragma unroll
      for (int u = 2; u < 4; u++) stage_unit(Bw, n0 + u * 64, K, kn2, Bc + u * 64 * 64, t);
    }
    {
      bf16x8 a00 = *(const bf16x8*)(Ac + aoff[4][0]);
      bf16x8 a01 = *(const bf16x8*)(Ac + aoff[4][1]);
      bf16x8 a10 = *(const bf16x8*)(Ac + aoff[5][0]);
      bf16x8 a11 = *(const bf16x8*)(Ac + aoff[5][1]);
      __builtin_amdgcn_s_barrier();
      asm volatile("s_waitcnt lgkmcnt(0)" ::: "memory");
      __builtin_amdgcn_sched_barrier(0);
      __builtin_amdgcn_s_setprio(1);
#pragma unroll
      for (int nf = 0; nf < 4; nf++) {
        acc[4][nf] = mfma16(a00, bfr[nf][0], acc[4][nf]);
        acc[4][nf] = mfma16(a01, bfr[nf][1], acc[4][nf]);
        acc[5][nf] = mfma16(a10, bfr[nf][0], acc[5][nf]);
        acc[5][nf] = mfma16(a11, bfr[nf][1], acc[5][nf]);
      }
      __builtin_amdgcn_s_setprio(0);
      __builtin_amdgcn_s_barrier();
    }
    // ---- phase 3 : counted vmcnt boundary wait; MFMA quadrant 3 (mf6,7) ----
    {
      bf16x8 a00 = *(const bf16x8*)(Ac + aoff[6][0]);
      bf16x8 a01 = *(const bf16x8*)(Ac + aoff[6][1]);
      bf16x8 a10 = *(const bf16x8*)(Ac + aoff[7][0]);
      bf16x8 a11 = *(const bf16x8*)(Ac + aoff[7][1]);
      if (pf2)      asm volatile("s_waitcnt vmcnt(4)" ::: "memory"); // retire A[T+1]; B[T+2] stays
      else if (pf1) asm volatile("s_waitcnt vmcnt(0)" ::: "memory"); // tail drain
      __builtin_amdgcn_s_barrier();                 // publish tile T+1
      asm volatile("s_waitcnt lgkmcnt(0)" ::: "memory");
      __builtin_amdgcn_sched_barrier(0);
      __builtin_amdgcn_s_setprio(1);
#pragma unroll
      for (int nf = 0; nf < 4; nf++) {
        acc[6][nf] = mfma16(a00, bfr[nf][0], acc[6][nf]);
        acc[6][nf] = mfma16(a01, bfr[nf][1], acc[6][nf]);
        acc[7][nf] = mfma16(a10, bfr[nf][0], acc[7][nf]);
        acc[7][nf] = mfma16(a11, bfr[nf][1], acc[7][nf]);
      }
      __builtin_amdgcn_s_setprio(0);
      __builtin_amdgcn_s_barrier();                 // WAR guard for next staging
    }
  }

  // epilogue (mapping identical to R12, harness-verified)
#pragma unroll
  for (int mf = 0; mf < 8; mf++)
#pragma unroll
    for (int nf = 0; nf < 4; nf++)
#pragma unroll
      for (int r = 0; r < 4; r++) {
        long row = m0 + wm * 128 + mf * 16 + quad * 4 + r;
        long col = n0 + wn * 64 + nf * 16 + l15;
        float v = acc[mf][nf][r];
        if constexpr (sizeof(OutT) == 2) C[row * (long)N + col] = (OutT)(__bf16)v;
        else                             C[row * (long)N + col] = v;
      }
}

// ---------------------------------------------------------------------------
// 256x128 triple-buffered 2-phase GEMM (O-proj; R10, unchanged).
// ---------------------------------------------------------------------------
template <typename OutT>
__global__ __launch_bounds__(512, 2) void gemm_bt8(
    const __bf16* __restrict__ A, const __bf16* __restrict__ Bw,
    OutT* __restrict__ C, int M, int N, int K, int NX) {
  __shared__ __align__(16) __bf16 As[3][256 * 64];
  __shared__ __align__(16) __bf16 Bs[3][128 * 64];
  const int t = threadIdx.x;
  const int lane = t & 63, w = t >> 6;
  const int wm = w >> 1, wn = w & 1;        // 4M x 2N waves
  const int l15 = lane & 15, quad = lane >> 4;

  const int bid = blockIdx.x;
  const int cpx = gridDim.x >> 3;
  const int swz = (bid & 7) * cpx + (bid >> 3);
  const long m0 = (long)(swz / NX) * 256;
  const long n0 = (long)(swz % NX) * 128;

  int aoff[4][2], boff[4][2];
#pragma unroll
  for (int mf = 0; mf < 4; mf++)
#pragma unroll
    for (int ks = 0; ks < 2; ks++)
      aoff[mf][ks] = (wm * 64 + mf * 16 + l15) * 64 + (((ks * 4 + quad) ^ (l15 & 7)) << 3);
#pragma unroll
  for (int nf = 0; nf < 4; nf++)
#pragma unroll
    for (int ks = 0; ks < 2; ks++)
      boff[nf][ks] = (wn * 64 + nf * 16 + l15) * 64 + (((ks * 4 + quad) ^ (l15 & 7)) << 3);

  const int NT = K >> 6;
  __bf16 *Ac = As[0], *An = As[1], *Asg = As[2];
  __bf16 *Bc = Bs[0], *Bn = Bs[1], *Bsg = Bs[2];

#pragma unroll
  for (int u = 0; u < 4; u++) stage_unit(A, m0 + u * 64, K, 0, Ac + u * 64 * 64, t);
#pragma unroll
  for (int u = 0; u < 2; u++) stage_unit(Bw, n0 + u * 64, K, 0, Bc + u * 64 * 64, t);
#pragma unroll
  for (int u = 0; u < 4; u++) stage_unit(A, m0 + u * 64, K, 64, An + u * 64 * 64, t);
#pragma unroll
  for (int u = 0; u < 2; u++) stage_unit(Bw, n0 + u * 64, K, 64, Bn + u * 64 * 64, t);
  asm volatile("s_waitcnt vmcnt(6)" ::: "memory");
  __builtin_amdgcn_s_barrier();

  f32x4 acc[4][4] = {};
  for (int T = 0; T < NT; T++) {
    const bool pf2 = (T + 2 < NT);
    const long kn2 = (long)(T + 2) * 64;

    bf16x8 bfr[4][2];
#pragma unroll
    for (int nf = 0; nf < 4; nf++)
#pragma unroll
      for (int ks = 0; ks < 2; ks++)
        bfr[nf][ks] = *(const bf16x8*)(Bc + boff[nf][ks]);
    {
      bf16x8 a00 = *(const bf16x8*)(Ac + aoff[0][0]);
      bf16x8 a01 = *(const bf16x8*)(Ac + aoff[0][1]);
      bf16x8 a10 = *(const bf16x8*)(Ac + aoff[1][0]);
      bf16x8 a11 = *(const bf16x8*)(Ac + aoff[1][1]);
      if (pf2) {
#pragma unroll
        for (int u = 0; u < 4; u++)
          stage_unit(A, m0 + u * 64, K, kn2, Asg + u * 64 * 64, t);
      }
      __builtin_amdgcn_s_barrier();
      asm volatile("s_waitcnt lgkmcnt(0)" ::: "memory");
      __builtin_amdgcn_sched_barrier(0);
      __builtin_amdgcn_s_setprio(1);
#pragma unroll
      for (int nf = 0; nf < 4; nf++) {
        acc[0][nf] = mfma16(a00, bfr[nf][0], acc[0][nf]);
        acc[0][nf] = mfma16(a01, bfr[nf][1], acc[0][nf]);
        acc[1][nf] = mfma16(a10, bfr[nf][0], acc[1][nf]);
        acc[1][nf] = mfma16(a11, bfr[nf][1], acc[1][nf]);
      }
      __builtin_amdgcn_s_setprio(0);
      __builtin_amdgcn_s_barrier();
    }
    {
      bf16x8 a00 = *(const bf16x8*)(Ac + aoff[2][0]);
      bf16x8 a01 = *(const bf16x8*)(Ac + aoff[2][1]);
      bf16x8 a10 = *(const bf16x8*)(Ac + aoff[3][0]);
      bf16x8 a11 = *(const bf16x8*)(Ac + aoff[3][1]);
      if (pf2) {
#pragma unroll
        for (int u = 0; u < 2; u++)
          stage_unit(Bw, n0 + u * 64, K, kn2, Bsg + u * 64 * 64, t);
        asm volatile("s_waitcnt vmcnt(6)" ::: "memory");
      } else {
        asm volatile("s_waitcnt vmcnt(0)" ::: "memory");
      }
      __builtin_amdgcn_s_barrier();
      asm volatile("s_waitcnt lgkmcnt(0)" ::: "memory");
      __builtin_amdgcn_sched_barrier(0);
      __builtin_amdgcn_s_setprio(1);
#pragma unroll
      for (int nf = 0; nf < 4; nf++) {
        acc[2][nf] = mfma16(a00, bfr[nf][0], acc[2][nf]);
        acc[2][nf] = mfma16(a01, bfr[nf][1], acc[2][nf]);
        acc[3][nf] = mfma16(a10, bfr[nf][0], acc[3][nf]);
        acc[3][nf] = mfma16(a11, bfr[nf][1], acc[3][nf]);
      }
      __builtin_amdgcn_s_setprio(0);
      __builtin_amdgcn_s_barrier();
    }
    __bf16* ta = Ac; Ac = An; An = Asg; Asg = ta;
    __bf16* tb = Bc; Bc = Bn; Bn = Bsg; Bsg = tb;
  }

#pragma unroll
  for (int mf = 0; mf < 4; mf++)
#pragma unroll
    for (int nf = 0; nf < 4; nf++)
#pragma unroll
      for (int r = 0; r < 4; r++) {
        long row = m0 + wm * 64 + mf * 16 + quad * 4 + r;
        long col = n0 + wn * 64 + nf * 16 + l15;
        float v = acc[mf][nf][r];
        if constexpr (sizeof(OutT) == 2) C[row * (long)N + col] = (OutT)(__bf16)v;
        else                             C[row * (long)N + col] = v;
      }
}

// ---------------------------------------------------------------------------
// V transpose: QKV[b][s][2048 + h*64 + d] -> VT[(b*16+h)*64 + d][s]
// ---------------------------------------------------------------------------
__global__ __launch_bounds__(256) void vtrans(
    const __bf16* __restrict__ QKV, __bf16* __restrict__ VT) {
  constexpr int LDs = 136;
  __shared__ __align__(16) __bf16 Ts[64 * LDs];
  const int t = threadIdx.x;
  const int st0 = blockIdx.x * 128, h = blockIdx.y, b = blockIdx.z;
  const long vbase = (long)b * 2048 * 3072 + 2048 + h * 64;
#pragma unroll
  for (int i = 0; i < 4; i++) {
    int sl = i * 32 + (t >> 3), d0 = (t & 7) * 8;
    __bf16 tmp[8];
    *(uint4*)tmp = *(const uint4*)(QKV + vbase + (long)(st0 + sl) * 3072 + d0);
#pragma unroll
    for (int j = 0; j < 8; j++) Ts[(d0 + j) * LDs + sl] = tmp[j];
  }
  __syncthreads();
  const long obase = (long)(b * 16 + h) * 64 * 2048 + st0;
  const int d = t >> 2;
#pragma unroll
  for (int i = 0; i < 4; i++) {
    int sc = ((t & 3) + 4 * i) * 8;
    *(uint4*)(VT + obase + (long)d * 2048 + sc) = *(const uint4*)(Ts + d * LDs + sc);
  }
}

// ---------------------------------------------------------------------------
// Causal attention (R11, unchanged): XCD-locality swizzle + triple-buffered
// K/VT with counted vmcnt(4) + raw s_barrier; exp2, ones-column l.
// ---------------------------------------------------------------------------
__global__ __launch_bounds__(256) void attn4(
    const __bf16* __restrict__ QKV, const __bf16* __restrict__ VT,
    __bf16* __restrict__ O) {
  constexpr int SD = 3072;
  constexpr int LDP = 72;
  __shared__ __align__(16) __bf16 Ks[3][64 * 64];
  __shared__ __align__(16) __bf16 Vs[3][64 * 64];
  __shared__ __align__(16) __bf16 Pw[4 * 32 * LDP];
  const int t = threadIdx.x;
  const int lane = t & 63, w = t >> 6;
  const int l15 = lane & 15, quad = lane >> 4;

  const int bid = blockIdx.x;
  const int g = (bid & 7) * 8 + (bid >> 6);   // (h,b) group, 0..63
  const int jj = (bid >> 3) & 7;
  const int h = g & 15, b = g >> 4;

  const long qbase = (long)b * 2048 * SD + h * 64;
  const long kbase = qbase + 1024;
  const long vtbase = (long)(b * 16 + h) * 64 * 2048;
  __bf16* Pme = Pw + w * 32 * LDP;

  const int sr = w * 16 + (lane >> 3);
  const int scg = (lane & 7) ^ (sr & 7);
  const int ldsOff = (w * 16) * 64;
  const __bf16* gK = QKV + kbase + (long)sr * SD + scg * 8;
  const __bf16* gV = VT + vtbase + (long)sr * 2048 + scg * 8;

  int kvoff[4][2];
#pragma unroll
  for (int nt = 0; nt < 4; nt++)
#pragma unroll
    for (int kk = 0; kk < 2; kk++)
      kvoff[nt][kk] = (nt * 16 + l15) * 64 + (((kk * 4 + quad) ^ (l15 & 7)) << 3);

  bf16x8 ones;
#pragma unroll
  for (int j = 0; j < 8; j++) ones[j] = (__bf16)1.0f;

#pragma unroll
  for (int half = 0; half < 2; half++) {
    const int qt = half ? (15 - jj) : jj;
    const int q0 = qt * 128;
    const int wrow0 = q0 + w * 32;

    bf16x8 qf[2][2];
#pragma unroll
    for (int mt = 0; mt < 2; mt++)
#pragma unroll
      for (int kk = 0; kk < 2; kk++)
        qf[mt][kk] = *(const bf16x8*)(QKV + qbase +
            (long)(wrow0 + mt * 16 + l15) * SD + kk * 32 + quad * 8);

    f32x4 o_acc[2][4] = {};
    f32x4 o_l[2] = {};

    const int nkt = 2 * qt + 2;

    __syncthreads();
    load16_lds(gK, Ks[0] + ldsOff);
    load16_lds(gK + 8 * SD, Ks[0] + ldsOff + 8 * 64);
    load16_lds(gV, Vs[0] + ldsOff);
    load16_lds(gV + 8 * 2048, Vs[0] + ldsOff + 8 * 64);
    {
      const __bf16* gK1 = gK + (long)64 * SD;
      const __bf16* gV1 = gV + 64;
      load16_lds(gK1, Ks[1] + ldsOff);
      load16_lds(gK1 + 8 * SD, Ks[1] + ldsOff + 8 * 64);
      load16_lds(gV1, Vs[1] + ldsOff);
      load16_lds(gV1 + 8 * 2048, Vs[1] + ldsOff + 8 * 64);
    }

    int cur = 0;
    for (int kt = 0; kt < nkt; kt++) {
      if (kt + 1 < nkt) asm volatile("s_waitcnt vmcnt(4)" ::: "memory");
      else              asm volatile("s_waitcnt vmcnt(0)" ::: "memory");
      __builtin_amdgcn_s_barrier();
      __builtin_amdgcn_sched_barrier(0);

      if (kt + 2 < nkt) {
        int stg = cur + 2; if (stg >= 3) stg -= 3;
        const __bf16* gKn = gK + (long)(kt + 2) * 64 * SD;
        const __bf16* gVn = gV + (kt + 2) * 64;
        load16_lds(gKn, Ks[stg] + ldsOff);
        load16_lds(gKn + 8 * SD, Ks[stg] + ldsOff + 8 * 64);
        load16_lds(gVn, Vs[stg] + ldsOff);
        load16_lds(gVn + 8 * 2048, Vs[stg] + ldsOff + 8 * 64);
      }

      const int k0 = kt * 64;
      if (k0 <= wrow0 + 31) {
        const __bf16* KsB = Ks[cur];
        const __bf16* VsB = Vs[cur];
        bf16x8 kf[4][2];
#pragma unroll
        for (int nt = 0; nt < 4; nt++)
#pragma unroll
          for (int kk = 0; kk < 2; kk++)
            kf[nt][kk] = *(const bf16x8*)(KsB + kvoff[nt][kk]);
        f32x4 st[4][2];
        __builtin_amdgcn_s_setprio(1);
#pragma unroll
        for (int nt = 0; nt < 4; nt++)
#pragma unroll
          for (int mt = 0; mt < 2; mt++) {
            f32x4 z = {0.f, 0.f, 0.f, 0.f};
            z = mfma16(kf[nt][0], qf[mt][0], z);
            st[nt][mt] = mfma16(kf[nt][1], qf[mt][1], z);
          }
        __builtin_amdgcn_s_setprio(0);

        if (k0 + 63 <= wrow0) {
#pragma unroll
          for (int mt = 0; mt < 2; mt++)
#pragma unroll
            for (int nt = 0; nt < 4; nt++) {
              bf16x4 pb;
#pragma unroll
              for (int r = 0; r < 4; r++)
                pb[r] = (__bf16)__builtin_amdgcn_exp2f(st[nt][mt][r]);
              *(bf16x4*)(Pme + (mt * 16 + l15) * LDP + nt * 16 + quad * 4) = pb;
            }
        } else {
#pragma unroll
          for (int mt = 0; mt < 2; mt++) {
            const int qrow = wrow0 + mt * 16 + l15;
#pragma unroll
            for (int nt = 0; nt < 4; nt++) {
              const int keyb = k0 + nt * 16 + quad * 4;
              bf16x4 pb;
#pragma unroll
              for (int r = 0; r < 4; r++) {
                float e = __builtin_amdgcn_exp2f(st[nt][mt][r]);
                if (keyb + r > qrow) e = 0.f;
                pb[r] = (__bf16)e;
              }
              *(bf16x4*)(Pme + (mt * 16 + l15) * LDP + nt * 16 + quad * 4) = pb;
            }
          }
        }

#pragma unroll
        for (int kk = 0; kk < 2; kk++) {
          bf16x8 vf[4];
#pragma unroll
          for (int dt = 0; dt < 4; dt++)
            vf[dt] = *(const bf16x8*)(VsB + kvoff[dt][kk]);
#pragma unroll
          for (int mt = 0; mt < 2; mt++) {
            bf16x8 pf = *(const bf16x8*)(Pme + (mt * 16 + l15) * LDP + kk * 32 + quad * 8);
            __builtin_amdgcn_s_setprio(1);
#pragma unroll
            for (int dt = 0; dt < 4; dt++)
              o_acc[mt][dt] = mfma16(pf, vf[dt], o_acc[mt][dt]);
            o_l[mt] = mfma16(pf, ones, o_l[mt]);
            __builtin_amdgcn_s_setprio(0);
          }
        }
      }
      cur = (cur == 2) ? 0 : cur + 1;
    }

#pragma unroll
    for (int mt = 0; mt < 2; mt++) {
#pragma unroll
      for (int r = 0; r < 4; r++) {
        float inv = 1.f / o_l[mt][r];
        int row = wrow0 + mt * 16 + quad * 4 + r;
        long ob = ((long)b * 2048 + row) * 1024 + h * 64;
#pragma unroll
        for (int dt = 0; dt < 4; dt++)
          O[ob + dt * 16 + l15] = (__bf16)(o_acc[mt][dt][r] * inv);
      }
    }
  }
}

// ---------------------------------------------------------------------------
extern "C" void kernel_launch(void* const* d_in, const int* in_sizes, int n_in,
                              void* d_out, int out_size, void* d_ws, size_t ws_size,
                              hipStream_t stream) {
  const float* x  = (const float*)d_in[0];
  const float* wq = (const float*)d_in[1];
  const float* wk = (const float*)d_in[2];
  const float* wv = (const float*)d_in[3];
  const float* wo = (const float*)d_in[4];
  float* out = (float*)d_out;

  char* ws = (char*)d_ws;
  __bf16* xb   = (__bf16*)(ws);               // 16 MB [8192,1024]; reused as Ab
  __bf16* wqkv = (__bf16*)(ws + (16l << 20)); //  6 MB [3072,1024]
  __bf16* wob  = (__bf16*)(ws + (22l << 20)); //  2 MB
  __bf16* QKV  = (__bf16*)(ws + (24l << 20)); // 48 MB [8192,3072]
  __bf16* VT   = (__bf16*)(ws + (72l << 20)); // 16 MB [4096,2048] -> 88 MB total
  __bf16* Ab   = xb;                          // x dead after QKV gemm

  cvt_f32_bf16<<<4096, 256, 0, stream>>>(x, xb, 8192 * 1024 / 8);
  cvt_w<<<2048, 256, 0, stream>>>(wq, wk, wv, wo, wqkv, wob);

  // fused QKV projection: [8192,3072] = xb @ wqkv^T  (32x12 = 384 blocks, 256^2)
  gemm_bt8q<__bf16><<<384, 512, 0, stream>>>(xb, wqkv, QKV, 8192, 3072, 1024, 12);

  // V -> VT [b,h,d,s]
  vtrans<<<dim3(16, 16, 4), 256, 0, stream>>>(QKV, VT);

  // causal attention (XCD-grouped 1-D grid of 512) -> Ab
  attn4<<<512, 256, 0, stream>>>(QKV, VT, Ab);

  // output projection (fp32 out)  (256 blocks, 1 exact round)
  gemm_bt8<float><<<256, 512, 0, stream>>>(Ab, wob, out, 8192, 1024, 1024, 8);
}

// Round 7
// 229.482 us; speedup vs baseline: 1.1232x; 1.1232x over previous
//
#include <hip/hip_runtime.h>
#include <hip/hip_bf16.h>
#include <stdint.h>

// ---------------------------------------------------------------------------
// MetaMultiHeadSelfAttention: B=4, S=2048, D=1024, H=16, hd=64, causal.
// R14: abandon 256^2 GEMM experiments (R12/R13 both 80 us = packing-taxed).
// Revert all GEMMs to the proven R10 256x128 triple-buffer kernel and cut
// algorithm-level waste instead:
//   1. V^T computed DIRECTLY as a GEMM: VT[d][s] = sum_k Wv[d][k] x[s][k]
//      (A=Wv M=1024, Bw=x N=8192) -> vtrans kernel deleted; V written once
//      (was: write V + read V + write VT = +32 MB traffic).
//      QKV gemm shrinks to QK-only (N=2048, 512 blocks = 2 exact rounds);
//      VT gemm = 256 blocks = 1 exact round; O-proj = 256 = 1 round.
//   2. cvt_f32_bf16 + cvt_w merged into one launch (one fewer boundary).
//   3. attn4 = R11 version, strides adapted (QK row = 2048, VT row = 8192).
// ---------------------------------------------------------------------------

typedef __bf16 bf16x8 __attribute__((ext_vector_type(8)));
typedef __bf16 bf16x4 __attribute__((ext_vector_type(4)));
typedef float  f32x4  __attribute__((ext_vector_type(4)));

static __device__ __forceinline__ f32x4 mfma16(bf16x8 a, bf16x8 b, f32x4 c) {
  return __builtin_amdgcn_mfma_f32_16x16x32_bf16(a, b, c, 0, 0, 0);
}

// async 16B/lane global->LDS; LDS dest = wave-uniform base + lane*16
static __device__ __forceinline__ void load16_lds(const void* g, void* l) {
  __builtin_amdgcn_global_load_lds(
      (const __attribute__((address_space(1))) unsigned int*)g,
      (__attribute__((address_space(3))) unsigned int*)l, 16, 0, 0);
}

// ---------------------------------------------------------------------------
// fused cvt: blocks [0,4096) convert x (fp32->bf16, 8/thread);
// blocks [4096,6144) convert weights: wq (scaled by 0.125*log2e) -> wqk[0],
// wk -> wqk[1MB], wv -> wvb, wo -> wob.
// ---------------------------------------------------------------------------
__global__ __launch_bounds__(256) void cvt_all(
    const float* __restrict__ x,
    const float* __restrict__ w0, const float* __restrict__ w1,
    const float* __restrict__ w2, const float* __restrict__ w3,
    __bf16* __restrict__ xb, __bf16* __restrict__ wqk,
    __bf16* __restrict__ wvb, __bf16* __restrict__ wob) {
  const int blk = blockIdx.x;
  const int t = threadIdx.x;
  if (blk < 4096) {
    int i = blk * 256 + t;
    const float4* in4 = (const float4*)x;
    float4 a = in4[2 * i], b = in4[2 * i + 1];
    __bf16 v[8];
    v[0] = (__bf16)a.x; v[1] = (__bf16)a.y; v[2] = (__bf16)a.z; v[3] = (__bf16)a.w;
    v[4] = (__bf16)b.x; v[5] = (__bf16)b.y; v[6] = (__bf16)b.z; v[7] = (__bf16)b.w;
    *(bf16x8*)(xb + 8 * i) = *(bf16x8*)v;
  } else {
    int b2 = blk - 4096;               // 2048 blocks, 512 per matrix
    int m = b2 >> 9;
    const float* src = (m == 0) ? w0 : (m == 1) ? w1 : (m == 2) ? w2 : w3;
    __bf16* dst = (m == 0) ? wqk : (m == 1) ? (wqk + (size_t)(1024 * 1024))
                : (m == 2) ? wvb : wob;
    const float scl = (m == 0) ? 0.18033688011112042f : 1.0f;  // 0.125*log2(e)
    int i = (b2 & 511) * 256 + t;
    const float4* in4 = (const float4*)src;
    float4 a = in4[2 * i], b = in4[2 * i + 1];
    __bf16 v[8];
    v[0] = (__bf16)(a.x * scl); v[1] = (__bf16)(a.y * scl);
    v[2] = (__bf16)(a.z * scl); v[3] = (__bf16)(a.w * scl);
    v[4] = (__bf16)(b.x * scl); v[5] = (__bf16)(b.y * scl);
    v[6] = (__bf16)(b.z * scl); v[7] = (__bf16)(b.w * scl);
    *(bf16x8*)(dst + 8 * i) = *(bf16x8*)v;
  }
}

// ---------------------------------------------------------------------------
// stage unit: 64 rows x 64 cols bf16 (8 KB) = 1 global_load_lds / thread,
// chunk-XOR swizzle (16B chunk c of row r -> slot c ^ (r&7)).
// ---------------------------------------------------------------------------
static __device__ __forceinline__ void stage_unit(
    const __bf16* __restrict__ X, long grow0, int K, long k0,
    __bf16* lds, int t) {
  const int lane = t & 63, w = t >> 6;
  const int rl = w * 8 + (lane >> 3);                   // row within unit
  const int chunk = (lane & 7) ^ ((lane >> 3) & 7);     // row&7 == (lane>>3)&7
  load16_lds(X + (grow0 + rl) * (long)K + k0 + chunk * 8,
             lds + (w * 8) * 64);                       // wave-uniform base
}

// ---------------------------------------------------------------------------
// 256x128 triple-buffered 2-phase GEMM (R10, harness-verified):
// C[M,N] = A[M,K] @ Bw[N,K]^T. 512 threads = 8 waves (4M x 2N),
// per-wave 64x64. BK=64; LDS = 3 x (A[256][64] + B[128][64]) = 144 KiB.
// ---------------------------------------------------------------------------
template <typename OutT>
__global__ __launch_bounds__(512, 2) void gemm_bt8(
    const __bf16* __restrict__ A, const __bf16* __restrict__ Bw,
    OutT* __restrict__ C, int M, int N, int K, int NX) {
  __shared__ __align__(16) __bf16 As[3][256 * 64];
  __shared__ __align__(16) __bf16 Bs[3][128 * 64];
  const int t = threadIdx.x;
  const int lane = t & 63, w = t >> 6;
  const int wm = w >> 1, wn = w & 1;        // 4M x 2N waves
  const int l15 = lane & 15, quad = lane >> 4;

  const int bid = blockIdx.x;
  const int cpx = gridDim.x >> 3;
  const int swz = (bid & 7) * cpx + (bid >> 3);
  const long m0 = (long)(swz / NX) * 256;
  const long n0 = (long)(swz % NX) * 128;

  int aoff[4][2], boff[4][2];
#pragma unroll
  for (int mf = 0; mf < 4; mf++)
#pragma unroll
    for (int ks = 0; ks < 2; ks++)
      aoff[mf][ks] = (wm * 64 + mf * 16 + l15) * 64 + (((ks * 4 + quad) ^ (l15 & 7)) << 3);
#pragma unroll
  for (int nf = 0; nf < 4; nf++)
#pragma unroll
    for (int ks = 0; ks < 2; ks++)
      boff[nf][ks] = (wn * 64 + nf * 16 + l15) * 64 + (((ks * 4 + quad) ^ (l15 & 7)) << 3);

  const int NT = K >> 6;
  __bf16 *Ac = As[0], *An = As[1], *Asg = As[2];
  __bf16 *Bc = Bs[0], *Bn = Bs[1], *Bsg = Bs[2];

#pragma unroll
  for (int u = 0; u < 4; u++) stage_unit(A, m0 + u * 64, K, 0, Ac + u * 64 * 64, t);
#pragma unroll
  for (int u = 0; u < 2; u++) stage_unit(Bw, n0 + u * 64, K, 0, Bc + u * 64 * 64, t);
#pragma unroll
  for (int u = 0; u < 4; u++) stage_unit(A, m0 + u * 64, K, 64, An + u * 64 * 64, t);
#pragma unroll
  for (int u = 0; u < 2; u++) stage_unit(Bw, n0 + u * 64, K, 64, Bn + u * 64 * 64, t);
  asm volatile("s_waitcnt vmcnt(6)" ::: "memory");
  __builtin_amdgcn_s_barrier();

  f32x4 acc[4][4] = {};
  for (int T = 0; T < NT; T++) {
    const bool pf2 = (T + 2 < NT);
    const long kn2 = (long)(T + 2) * 64;

    bf16x8 bfr[4][2];
#pragma unroll
    for (int nf = 0; nf < 4; nf++)
#pragma unroll
      for (int ks = 0; ks < 2; ks++)
        bfr[nf][ks] = *(const bf16x8*)(Bc + boff[nf][ks]);
    {
      bf16x8 a00 = *(const bf16x8*)(Ac + aoff[0][0]);
      bf16x8 a01 = *(const bf16x8*)(Ac + aoff[0][1]);
      bf16x8 a10 = *(const bf16x8*)(Ac + aoff[1][0]);
      bf16x8 a11 = *(const bf16x8*)(Ac + aoff[1][1]);
      if (pf2) {
#pragma unroll
        for (int u = 0; u < 4; u++)
          stage_unit(A, m0 + u * 64, K, kn2, Asg + u * 64 * 64, t);
      }
      __builtin_amdgcn_s_barrier();
      asm volatile("s_waitcnt lgkmcnt(0)" ::: "memory");
      __builtin_amdgcn_sched_barrier(0);
      __builtin_amdgcn_s_setprio(1);
#pragma unroll
      for (int nf = 0; nf < 4; nf++) {
        acc[0][nf] = mfma16(a00, bfr[nf][0], acc[0][nf]);
        acc[0][nf] = mfma16(a01, bfr[nf][1], acc[0][nf]);
        acc[1][nf] = mfma16(a10, bfr[nf][0], acc[1][nf]);
        acc[1][nf] = mfma16(a11, bfr[nf][1], acc[1][nf]);
      }
      __builtin_amdgcn_s_setprio(0);
      __builtin_amdgcn_s_barrier();
    }
    {
      bf16x8 a00 = *(const bf16x8*)(Ac + aoff[2][0]);
      bf16x8 a01 = *(const bf16x8*)(Ac + aoff[2][1]);
      bf16x8 a10 = *(const bf16x8*)(Ac + aoff[3][0]);
      bf16x8 a11 = *(const bf16x8*)(Ac + aoff[3][1]);
      if (pf2) {
#pragma unroll
        for (int u = 0; u < 2; u++)
          stage_unit(Bw, n0 + u * 64, K, kn2, Bsg + u * 64 * 64, t);
        asm volatile("s_waitcnt vmcnt(6)" ::: "memory");
      } else {
        asm volatile("s_waitcnt vmcnt(0)" ::: "memory");
      }
      __builtin_amdgcn_s_barrier();
      asm volatile("s_waitcnt lgkmcnt(0)" ::: "memory");
      __builtin_amdgcn_sched_barrier(0);
      __builtin_amdgcn_s_setprio(1);
#pragma unroll
      for (int nf = 0; nf < 4; nf++) {
        acc[2][nf] = mfma16(a00, bfr[nf][0], acc[2][nf]);
        acc[2][nf] = mfma16(a01, bfr[nf][1], acc[2][nf]);
        acc[3][nf] = mfma16(a10, bfr[nf][0], acc[3][nf]);
        acc[3][nf] = mfma16(a11, bfr[nf][1], acc[3][nf]);
      }
      __builtin_amdgcn_s_setprio(0);
      __builtin_amdgcn_s_barrier();
    }
    __bf16* ta = Ac; Ac = An; An = Asg; Asg = ta;
    __bf16* tb = Bc; Bc = Bn; Bn = Bsg; Bsg = tb;
  }

#pragma unroll
  for (int mf = 0; mf < 4; mf++)
#pragma unroll
    for (int nf = 0; nf < 4; nf++)
#pragma unroll
      for (int r = 0; r < 4; r++) {
        long row = m0 + wm * 64 + mf * 16 + quad * 4 + r;
        long col = n0 + wn * 64 + nf * 16 + l15;
        float v = acc[mf][nf][r];
        if constexpr (sizeof(OutT) == 2) C[row * (long)N + col] = (OutT)(__bf16)v;
        else                             C[row * (long)N + col] = v;
      }
}

// ---------------------------------------------------------------------------
// Causal attention (R11 structure): XCD-locality swizzle + triple-buffered
// K/VT with counted vmcnt(4) + raw s_barrier; exp2, ones-column l.
// Strides adapted: QK rows = 2048 (Q cols 0..1023, K cols 1024..2047);
// VT is [1024][8192] (row = h*64+d, col = b*2048 + s).
// ---------------------------------------------------------------------------
__global__ __launch_bounds__(256) void attn4(
    const __bf16* __restrict__ QK, const __bf16* __restrict__ VT,
    __bf16* __restrict__ O) {
  constexpr int SD = 2048;
  constexpr int LDP = 72;
  __shared__ __align__(16) __bf16 Ks[3][64 * 64];
  __shared__ __align__(16) __bf16 Vs[3][64 * 64];
  __shared__ __align__(16) __bf16 Pw[4 * 32 * LDP];
  const int t = threadIdx.x;
  const int lane = t & 63, w = t >> 6;
  const int l15 = lane & 15, quad = lane >> 4;

  const int bid = blockIdx.x;
  const int g = (bid & 7) * 8 + (bid >> 6);   // (h,b) group, 0..63
  const int jj = (bid >> 3) & 7;
  const int h = g & 15, b = g >> 4;

  const long qbase = (long)b * 2048 * SD + h * 64;
  const long kbase = qbase + 1024;
  __bf16* Pme = Pw + w * 32 * LDP;

  const int sr = w * 16 + (lane >> 3);
  const int scg = (lane & 7) ^ (sr & 7);
  const int ldsOff = (w * 16) * 64;
  const __bf16* gK = QK + kbase + (long)sr * SD + scg * 8;
  // VT row = h*64 + d (d = sr), col base = b*2048
  const __bf16* gV = VT + (long)(h * 64 + sr) * 8192 + b * 2048 + scg * 8;

  int kvoff[4][2];
#pragma unroll
  for (int nt = 0; nt < 4; nt++)
#pragma unroll
    for (int kk = 0; kk < 2; kk++)
      kvoff[nt][kk] = (nt * 16 + l15) * 64 + (((kk * 4 + quad) ^ (l15 & 7)) << 3);

  bf16x8 ones;
#pragma unroll
  for (int j = 0; j < 8; j++) ones[j] = (__bf16)1.0f;

#pragma unroll
  for (int half = 0; half < 2; half++) {
    const int qt = half ? (15 - jj) : jj;
    const int q0 = qt * 128;
    const int wrow0 = q0 + w * 32;

    bf16x8 qf[2][2];
#pragma unroll
    for (int mt = 0; mt < 2; mt++)
#pragma unroll
      for (int kk = 0; kk < 2; kk++)
        qf[mt][kk] = *(const bf16x8*)(QK + qbase +
            (long)(wrow0 + mt * 16 + l15) * SD + kk * 32 + quad * 8);

    f32x4 o_acc[2][4] = {};
    f32x4 o_l[2] = {};

    const int nkt = 2 * qt + 2;

    __syncthreads();
    load16_lds(gK, Ks[0] + ldsOff);
    load16_lds(gK + 8 * SD, Ks[0] + ldsOff + 8 * 64);
    load16_lds(gV, Vs[0] + ldsOff);
    load16_lds(gV + 8 * 8192, Vs[0] + ldsOff + 8 * 64);
    {
      const __bf16* gK1 = gK + (long)64 * SD;
      const __bf16* gV1 = gV + 64;
      load16_lds(gK1, Ks[1] + ldsOff);
      load16_lds(gK1 + 8 * SD, Ks[1] + ldsOff + 8 * 64);
      load16_lds(gV1, Vs[1] + ldsOff);
      load16_lds(gV1 + 8 * 8192, Vs[1] + ldsOff + 8 * 64);
    }

    int cur = 0;
    for (int kt = 0; kt < nkt; kt++) {
      if (kt + 1 < nkt) asm volatile("s_waitcnt vmcnt(4)" ::: "memory");
      else              asm volatile("s_waitcnt vmcnt(0)" ::: "memory");
      __builtin_amdgcn_s_barrier();
      __builtin_amdgcn_sched_barrier(0);

      if (kt + 2 < nkt) {
        int stg = cur + 2; if (stg >= 3) stg -= 3;
        const __bf16* gKn = gK + (long)(kt + 2) * 64 * SD;
        const __bf16* gVn = gV + (kt + 2) * 64;
        load16_lds(gKn, Ks[stg] + ldsOff);
        load16_lds(gKn + 8 * SD, Ks[stg] + ldsOff + 8 * 64);
        load16_lds(gVn, Vs[stg] + ldsOff);
        load16_lds(gVn + 8 * 8192, Vs[stg] + ldsOff + 8 * 64);
      }

      const int k0 = kt * 64;
      if (k0 <= wrow0 + 31) {
        const __bf16* KsB = Ks[cur];
        const __bf16* VsB = Vs[cur];
        bf16x8 kf[4][2];
#pragma unroll
        for (int nt = 0; nt < 4; nt++)
#pragma unroll
          for (int kk = 0; kk < 2; kk++)
            kf[nt][kk] = *(const bf16x8*)(KsB + kvoff[nt][kk]);
        f32x4 st[4][2];
        __builtin_amdgcn_s_setprio(1);
#pragma unroll
        for (int nt = 0; nt < 4; nt++)
#pragma unroll
          for (int mt = 0; mt < 2; mt++) {
            f32x4 z = {0.f, 0.f, 0.f, 0.f};
            z = mfma16(kf[nt][0], qf[mt][0], z);
            st[nt][mt] = mfma16(kf[nt][1], qf[mt][1], z);
          }
        __builtin_amdgcn_s_setprio(0);

        if (k0 + 63 <= wrow0) {
#pragma unroll
          for (int mt = 0; mt < 2; mt++)
#pragma unroll
            for (int nt = 0; nt < 4; nt++) {
              bf16x4 pb;
#pragma unroll
              for (int r = 0; r < 4; r++)
                pb[r] = (__bf16)__builtin_amdgcn_exp2f(st[nt][mt][r]);
              *(bf16x4*)(Pme + (mt * 16 + l15) * LDP + nt * 16 + quad * 4) = pb;
            }
        } else {
#pragma unroll
          for (int mt = 0; mt < 2; mt++) {
            const int qrow = wrow0 + mt * 16 + l15;
#pragma unroll
            for (int nt = 0; nt < 4; nt++) {
              const int keyb = k0 + nt * 16 + quad * 4;
              bf16x4 pb;
#pragma unroll
              for (int r = 0; r < 4; r++) {
                float e = __builtin_amdgcn_exp2f(st[nt][mt][r]);
                if (keyb + r > qrow) e = 0.f;
                pb[r] = (__bf16)e;
              }
              *(bf16x4*)(Pme + (mt * 16 + l15) * LDP + nt * 16 + quad * 4) = pb;
            }
          }
        }

#pragma unroll
        for (int kk = 0; kk < 2; kk++) {
          bf16x8 vf[4];
#pragma unroll
          for (int dt = 0; dt < 4; dt++)
            vf[dt] = *(const bf16x8*)(VsB + kvoff[dt][kk]);
#pragma unroll
          for (int mt = 0; mt < 2; mt++) {
            bf16x8 pf = *(const bf16x8*)(Pme + (mt * 16 + l15) * LDP + kk * 32 + quad * 8);
            __builtin_amdgcn_s_setprio(1);
#pragma unroll
            for (int dt = 0; dt < 4; dt++)
              o_acc[mt][dt] = mfma16(pf, vf[dt], o_acc[mt][dt]);
            o_l[mt] = mfma16(pf, ones, o_l[mt]);
            __builtin_amdgcn_s_setprio(0);
          }
        }
      }
      cur = (cur == 2) ? 0 : cur + 1;
    }

#pragma unroll
    for (int mt = 0; mt < 2; mt++) {
#pragma unroll
      for (int r = 0; r < 4; r++) {
        float inv = 1.f / o_l[mt][r];
        int row = wrow0 + mt * 16 + quad * 4 + r;
        long ob = ((long)b * 2048 + row) * 1024 + h * 64;
#pragma unroll
        for (int dt = 0; dt < 4; dt++)
          O[ob + dt * 16 + l15] = (__bf16)(o_acc[mt][dt][r] * inv);
      }
    }
  }
}

// ---------------------------------------------------------------------------
extern "C" void kernel_launch(void* const* d_in, const int* in_sizes, int n_in,
                              void* d_out, int out_size, void* d_ws, size_t ws_size,
                              hipStream_t stream) {
  const float* x  = (const float*)d_in[0];
  const float* wq = (const float*)d_in[1];
  const float* wk = (const float*)d_in[2];
  const float* wv = (const float*)d_in[3];
  const float* wo = (const float*)d_in[4];
  float* out = (float*)d_out;

  char* ws = (char*)d_ws;
  __bf16* xb   = (__bf16*)(ws);               // 16 MB [8192,1024]; reused as Ab
  __bf16* wqk  = (__bf16*)(ws + (16l << 20)); //  4 MB [2048,1024] (wq,wk)
  __bf16* wvb  = (__bf16*)(ws + (20l << 20)); //  2 MB [1024,1024]
  __bf16* wob  = (__bf16*)(ws + (22l << 20)); //  2 MB [1024,1024]
  __bf16* QK   = (__bf16*)(ws + (24l << 20)); // 32 MB [8192,2048]
  __bf16* VTg  = (__bf16*)(ws + (56l << 20)); // 16 MB [1024,8192] -> 72 MB total
  __bf16* Ab   = xb;                          // x dead after both input gemms

  // fused conversions (x + all 4 weights), one launch
  cvt_all<<<6144, 256, 0, stream>>>(x, wq, wk, wv, wo, xb, wqk, wvb, wob);

  // QK projection: [8192,2048] = xb @ wqk^T   (32x16 = 512 blocks, 2 exact rounds)
  gemm_bt8<__bf16><<<512, 512, 0, stream>>>(xb, wqk, QK, 8192, 2048, 1024, 16);

  // V^T direct: [1024,8192] = wvb @ xb^T      (4x64 = 256 blocks, 1 exact round)
  gemm_bt8<__bf16><<<256, 512, 0, stream>>>(wvb, xb, VTg, 1024, 8192, 1024, 64);

  // causal attention (XCD-grouped 1-D grid of 512) -> Ab
  attn4<<<512, 256, 0, stream>>>(QK, VTg, Ab);

  // output projection (fp32 out)              (32x8 = 256 blocks, 1 exact round)
  gemm_bt8<float><<<256, 512, 0, stream>>>(Ab, wob, out, 8192, 1024, 1024, 8);
}